// Round 12
// baseline (683.930 us; speedup 1.0000x reference)
//
#include <hip/hip_runtime.h>

#define NREL 8
#define NNODE 100000
#define TNODE 50000
#define NEDGE 800000
#define C 128
#define TILE_T 64
#define NTILE ((TNODE + TILE_T - 1) / TILE_T)   // 782
#define NENT (NREL * TNODE)                     // 400000
#define NB_SCAN ((NNODE + 255) / 256)           // 391
#define NSHARD 8

typedef unsigned int u32;
typedef unsigned short u16;
typedef __attribute__((ext_vector_type(8))) short bf16x8;
typedef __attribute__((ext_vector_type(4))) float f32x4;
typedef __attribute__((ext_vector_type(2))) float f32x2;

__device__ __forceinline__ u16 f2bf(float f) {
    union { float f; u32 u; } c; c.f = f;
    u32 u = c.u + 0x7FFFu + ((c.u >> 16) & 1u);   // RNE
    return (u16)(u >> 16);
}
__device__ __forceinline__ u32 pack2(float a, float b) {
    return (u32)f2bf(a) | ((u32)f2bf(b) << 16);
}
__device__ __forceinline__ float2 unpack_bf2(u32 p) {
    union { u32 u; float f; } a, b;
    a.u = p << 16; b.u = p & 0xFFFF0000u;
    return make_float2(a.f, b.f);
}
__device__ __forceinline__ f32x2 bits2(u32 p) {
    union { u32 u[2]; f32x2 f; } c;
    c.u[0] = p << 16; c.u[1] = p & 0xFFFF0000u;
    return c.f;
}
__device__ __forceinline__ void addp(f32x2* a, uint4 v) {
    a[0] += bits2(v.x); a[1] += bits2(v.y);
    a[2] += bits2(v.z); a[3] += bits2(v.w);
}
__device__ __forceinline__ void fma4(float4& acc, float a, float w0, float w1, float w2, float w3) {
    acc.x = fmaf(a, w0, acc.x);
    acc.y = fmaf(a, w1, acc.y);
    acc.z = fmaf(a, w2, acc.z);
    acc.w = fmaf(a, w3, acc.w);
}

// ---------------- kernel 1a: x f32 -> bf16, SHARD-MAJOR [8][NNODE][16] ----------------
__global__ __launch_bounds__(256)
void convert_x_shard_kernel(const float* __restrict__ x, u16* __restrict__ xbS) {
    int j = blockIdx.x * 256 + threadIdx.x;
    if (j >= NSHARD * NNODE) return;
    const int sh = j / NNODE;
    const int node = j - sh * NNODE;
    const float4* src = (const float4*)(x + (size_t)node * C + sh * 16);
    u16* dst = xbS + (size_t)j * 16;
    #pragma unroll
    for (int h = 0; h < 2; ++h) {
        const float4 v0 = src[h * 2], v1 = src[h * 2 + 1];
        uint4 o;
        o.x = pack2(v0.x, v0.y); o.y = pack2(v0.z, v0.w);
        o.z = pack2(v1.x, v1.y); o.w = pack2(v1.z, v1.w);
        *(uint4*)(dst + h * 8) = o;
    }
}

// ---------------- kernel 1a': row-major bf16 x (tier-2 fallback only) ----------------
__global__ __launch_bounds__(256)
void convert_x_kernel(const float* __restrict__ x, u16* __restrict__ xb, int n4) {
    int i = blockIdx.x * 256 + threadIdx.x;
    const int stride = gridDim.x * 256;
    for (; i < n4; i += stride) {
        const float4 v = ((const float4*)x)[i];
        ushort4 o;
        o.x = f2bf(v.x); o.y = f2bf(v.y); o.z = f2bf(v.z); o.w = f2bf(v.w);
        ((ushort4*)xb)[i] = o;
    }
}

// ---------------- kernel 1b: W f32 [r][k][c] -> bf16 W^T [r][c][k] ----------------
__global__ __launch_bounds__(256)
void convert_w_kernel(const float* __restrict__ w, u16* __restrict__ wtb) {
    const int o = blockIdx.x * 256 + threadIdx.x;
    if (o < NREL * C * C) {
        const int r = o >> 14, rem = o & 16383, cc = rem >> 7, k = rem & 127;
        wtb[o] = f2bf(w[(r << 14) + k * C + cc]);
    }
}

// ---------------- inverted-index build ----------------
__global__ __launch_bounds__(256)
void hist_kernel(const int* __restrict__ tgt, int* __restrict__ count) {
    const int g = blockIdx.x * 256 + threadIdx.x;
    if (g < NENT) atomicAdd(&count[tgt[g]], 1);
}

__global__ __launch_bounds__(256)
void scan1_kernel(const int* __restrict__ count, int* __restrict__ bsum) {
    __shared__ int s[256];
    const int tid = threadIdx.x;
    const int i = blockIdx.x * 256 + tid;
    s[tid] = (i < NNODE) ? count[i] : 0;
    __syncthreads();
    for (int st = 128; st > 0; st >>= 1) {
        if (tid < st) s[tid] += s[tid + st];
        __syncthreads();
    }
    if (tid == 0) bsum[blockIdx.x] = s[0];
}

__global__ __launch_bounds__(512)
void scan2_kernel(int* __restrict__ bsum) {
    __shared__ int s[512];
    const int tid = threadIdx.x;
    const int v = (tid < NB_SCAN) ? bsum[tid] : 0;
    s[tid] = v;
    __syncthreads();
    for (int st = 1; st < 512; st <<= 1) {
        const int t = (tid >= st) ? s[tid - st] : 0;
        __syncthreads();
        s[tid] += t;
        __syncthreads();
    }
    if (tid < NB_SCAN) bsum[tid] = s[tid] - v;   // exclusive
}

__global__ __launch_bounds__(256)
void scan3_kernel(const int* __restrict__ count, const int* __restrict__ bsum,
                  int* __restrict__ offsets, int* __restrict__ cursor) {
    __shared__ int s[256];
    const int tid = threadIdx.x;
    const int i = blockIdx.x * 256 + tid;
    const int v = (i < NNODE) ? count[i] : 0;
    s[tid] = v;
    __syncthreads();
    for (int st = 1; st < 256; st <<= 1) {
        const int t = (tid >= st) ? s[tid - st] : 0;
        __syncthreads();
        s[tid] += t;
        __syncthreads();
    }
    if (i < NNODE) {
        const int off = bsum[blockIdx.x] + s[tid] - v;
        offsets[i] = off;
        cursor[i]  = off;
    }
}

__global__ __launch_bounds__(256)
void fill_kernel(const int* __restrict__ tgt, int* __restrict__ cursor, int* __restrict__ list) {
    const int g = blockIdx.x * 256 + threadIdx.x;
    if (g < NENT) {
        const int pos = atomicAdd(&cursor[tgt[g]], 1);
        list[pos] = g;
    }
}

// ---------------- kernel 2: XCD-sharded gather -> aggS [8][NENT][16] bf16 ----------------
// BISECTION VERSION: shuffle-free, round-9-proven pattern. shard = blockIdx.x & 7
// (pinned to one XCD by round-robin dispatch; 3.2 MB x-slice L2-resident).
// 256 threads = 4 waves x 8 groups of 8 lanes; each group serially processes 2 targets;
// lane c owns col-pair [c*2, c*2+1]; 4 independent edge loads in flight; no cross-lane ops.
__global__ __launch_bounds__(256)
void gather_shard_kernel(const u16* __restrict__ xbS, const int* __restrict__ ptr,
                         const int* __restrict__ idx, u16* __restrict__ aggS) {
    const int b    = blockIdx.x;
    const int sh   = b & 7;
    const int item = b >> 3;
    const int rel  = item / NTILE;
    const int tile = item - rel * NTILE;

    const int lane = threadIdx.x & 63;
    const int w    = threadIdx.x >> 6;   // 4 waves
    const int grp  = lane >> 3;          // 8 groups per wave
    const int c    = lane & 7;           // col pair [c*2, c*2+1] of the 16-col shard row

    const int* pr = ptr + rel * (TNODE + 1);
    const int* er = idx + (size_t)rel * NEDGE;
    const u16* xs = xbS + (size_t)sh * NNODE * 16 + c * 2;
    u16* as = aggS + (size_t)sh * NENT * 16;

    #pragma unroll
    for (int half = 0; half < 2; ++half) {
        const int tl = w * 16 + half * 8 + grp;
        const int t  = tile * TILE_T + tl;
        if (t >= TNODE) continue;
        // clip(searchsorted(ptr,e,'right')-1, 0, T-1):
        //   t==0 owns [0, ptr[1]); t==T-1 owns [ptr[T-1], E)
        int s        = (t == 0) ? 0 : pr[t];
        const int e1 = (t == TNODE - 1) ? NEDGE : pr[t + 1];

        f32x2 a0 = (f32x2){0.f, 0.f}, a1 = (f32x2){0.f, 0.f};
        for (; s + 4 <= e1; s += 4) {            // 4 independent loads in flight
            const int i0 = er[s], i1 = er[s + 1], i2 = er[s + 2], i3 = er[s + 3];
            const u32 v0 = *(const u32*)(xs + (size_t)i0 * 16);
            const u32 v1 = *(const u32*)(xs + (size_t)i1 * 16);
            const u32 v2 = *(const u32*)(xs + (size_t)i2 * 16);
            const u32 v3 = *(const u32*)(xs + (size_t)i3 * 16);
            a0 += bits2(v0); a1 += bits2(v1);
            a0 += bits2(v2); a1 += bits2(v3);
        }
        for (; s < e1; ++s) {
            const u32 v0 = *(const u32*)(xs + (size_t)er[s] * 16);
            a0 += bits2(v0);
        }
        a0 += a1;

        const int g = rel * TNODE + t;
        *(u32*)(as + (size_t)g * 16 + c * 2) = pack2(a0.x, a0.y);
    }
}

// ---------------- kernel 3: MFMA bf16 GEMM, aggS -> P [NENT][128] bf16 ----------------
__global__ __launch_bounds__(256, 3)
void gemm_mfma_kernel(const u16* __restrict__ aggS, const u16* __restrict__ wtb,
                      u16* __restrict__ P) {
    __shared__ u16 sB[C * 136];        // 34816 B: W^T [col][k+pad]
    __shared__ u16 sA[TILE_T * 136];   // 17408 B: A tile / output tile

    const int tid  = threadIdx.x;
    const int tile = blockIdx.x;
    const int r    = blockIdx.y;

    // stage W^T
    {
        const uint4* src = (const uint4*)(wtb + (size_t)r * C * C);
        #pragma unroll
        for (int i = 0; i < 8; ++i) {
            const int f = tid + i * 256;
            const int col = f >> 4, unit = f & 15;
            *(uint4*)(sB + col * 136 + unit * 8) = src[f];
        }
    }
    // stage A tile from the 8 shard regions (32 B per (row, shard) unit)
    {
        #pragma unroll
        for (int k = 0; k < 2; ++k) {
            const int u = tid + k * 256;       // 512 units
            const int row = u >> 3, sh = u & 7;
            const int t = tile * TILE_T + row;
            u16* dst = sA + row * 136 + sh * 16;
            if (t < TNODE) {
                const u16* src = aggS + ((size_t)sh * NENT + (size_t)r * TNODE + t) * 16;
                *(uint4*)dst       = *(const uint4*)src;
                *(uint4*)(dst + 8) = *(const uint4*)(src + 8);
            } else {
                *(uint4*)dst       = make_uint4(0u, 0u, 0u, 0u);
                *(uint4*)(dst + 8) = make_uint4(0u, 0u, 0u, 0u);
            }
        }
    }
    __syncthreads();

    const int lane = tid & 63;
    const int wr   = (tid >> 6) * 16;
    const int fr   = lane & 15;
    const int fq   = lane >> 4;

    f32x4 acc[8];
    #pragma unroll
    for (int cf = 0; cf < 8; ++cf) acc[cf] = (f32x4){0.f, 0.f, 0.f, 0.f};

    #pragma unroll
    for (int ks = 0; ks < 4; ++ks) {
        const bf16x8 a = *(const bf16x8*)(sA + (wr + fr) * 136 + ks * 32 + fq * 8);
        #pragma unroll
        for (int cf = 0; cf < 8; ++cf) {
            const bf16x8 b = *(const bf16x8*)(sB + (cf * 16 + fr) * 136 + ks * 32 + fq * 8);
            acc[cf] = __builtin_amdgcn_mfma_f32_16x16x32_bf16(a, b, acc[cf], 0, 0, 0);
        }
    }
    __syncthreads();

    // D -> sA as bf16 (C/D layout: col=lane&15, row=(lane>>4)*4+reg)
    #pragma unroll
    for (int cf = 0; cf < 8; ++cf) {
        #pragma unroll
        for (int j = 0; j < 4; ++j) {
            const int row = wr + fq * 4 + j;
            sA[row * 136 + cf * 16 + fr] = f2bf(acc[cf][j]);
        }
    }
    __syncthreads();

    #pragma unroll
    for (int i = 0; i < 4; ++i) {
        const int f = tid + i * 256;
        const int row = f >> 4, unit = f & 15;
        const int t = tile * TILE_T + row;
        if (t < TNODE)
            *(uint4*)(P + ((size_t)r * TNODE + t) * C + unit * 8) =
                *(const uint4*)(sA + row * 136 + unit * 8);
    }
}

// ---------------- kernel 4: per-node gather of bf16 arr rows (no atomics) ----------------
__global__ __launch_bounds__(256)
void out_gather_kernel(const u16* __restrict__ P, const int* __restrict__ offsets,
                       const int* __restrict__ count, const int* __restrict__ list,
                       float* __restrict__ out) {
    const int lane = threadIdx.x & 63;
    const int n = blockIdx.x * 4 + (threadIdx.x >> 6);
    if (n >= NNODE) return;
    const int st = offsets[n];
    const int en = st + count[n];
    float2 a0 = make_float2(0.f, 0.f), a1 = make_float2(0.f, 0.f);
    int i = st;
    for (; i + 2 <= en; i += 2) {
        const u32 v0 = ((const u32*)(P + (size_t)list[i] * C))[lane];
        const u32 v1 = ((const u32*)(P + (size_t)list[i + 1] * C))[lane];
        const float2 f0 = unpack_bf2(v0), f1 = unpack_bf2(v1);
        a0.x += f0.x; a0.y += f0.y;
        a1.x += f1.x; a1.y += f1.y;
    }
    if (i < en) {
        const float2 f0 = unpack_bf2(((const u32*)(P + (size_t)list[i] * C))[lane]);
        a0.x += f0.x; a0.y += f0.y;
    }
    a0.x += a1.x; a0.y += a1.y;
    ((float2*)(out + (size_t)n * C))[lane] = a0;
}

// ---------------- tier-2: round-8 fused gather+GEMM (bf16 row-major xb) ----------------
__global__ __launch_bounds__(512, 6)
void fused_gather_gemm_kernel(const u16* __restrict__ xb, const int* __restrict__ ptr,
                              const int* __restrict__ idx, const u16* __restrict__ wtb,
                              u16* __restrict__ P) {
    __shared__ u16 sB[C * 136];
    __shared__ u16 sA[TILE_T * 136];
    __shared__ int qcount;

    const int tid  = threadIdx.x;
    const int tile = blockIdx.x;
    const int r    = blockIdx.y;
    const int w    = tid >> 6;
    const int lane = tid & 63;

    {
        const uint4* src = (const uint4*)(wtb + (size_t)r * C * C);
        #pragma unroll
        for (int i = 0; i < 4; ++i) {
            const int f = tid + i * 512;
            const int col = f >> 4, unit = f & 15;
            *(uint4*)(sB + col * 136 + unit * 8) = src[f];
        }
    }
    if (tid == 0) qcount = 0;
    __syncthreads();

    const int* pr = ptr + r * (TNODE + 1);
    const int* er = idx + (size_t)r * NEDGE;
    const int q  = lane >> 4;
    const int sl = lane & 15;
    const u16* xcol = xb + sl * 8;

    for (;;) {
        int tl;
        if (lane == 0) tl = atomicAdd(&qcount, 1);
        tl = __shfl(tl, 0);
        if (tl >= TILE_T) break;

        const int t = tile * TILE_T + tl;
        f32x2 accA[4], accB[4];
        #pragma unroll
        for (int j = 0; j < 4; ++j) { accA[j] = (f32x2){0.f, 0.f}; accB[j] = (f32x2){0.f, 0.f}; }

        if (t < TNODE) {
            const int start = (t == 0) ? 0 : pr[t];
            const int end   = (t == TNODE - 1) ? NEDGE : pr[t + 1];
            for (int base = start; base < end; base += 64) {
                const int cnt = min(end - base, 64);
                int myi = (lane < cnt) ? er[base + lane] : 0;
                int i = 0;
                for (; i + 8 <= cnt; i += 8) {
                    const int sA0 = __shfl(myi, i + q);
                    const int sB0 = __shfl(myi, i + 4 + q);
                    const uint4 vA = *(const uint4*)(xcol + (size_t)sA0 * C);
                    const uint4 vB = *(const uint4*)(xcol + (size_t)sB0 * C);
                    addp(accA, vA);
                    addp(accB, vB);
                }
                if (i + 4 <= cnt) {
                    const int sA0 = __shfl(myi, i + q);
                    const uint4 vA = *(const uint4*)(xcol + (size_t)sA0 * C);
                    addp(accA, vA);
                    i += 4;
                }
                if (i < cnt) {
                    const int rem = cnt - i;
                    const int sA0 = __shfl(myi, i + ((q < rem) ? q : 0));
                    if (q < rem) {
                        const uint4 vA = *(const uint4*)(xcol + (size_t)sA0 * C);
                        addp(accA, vA);
                    }
                }
            }
        }
        #pragma unroll
        for (int j = 0; j < 4; ++j) {
            accA[j] += accB[j];
            accA[j].x += __shfl_xor(accA[j].x, 16);
            accA[j].y += __shfl_xor(accA[j].y, 16);
            accA[j].x += __shfl_xor(accA[j].x, 32);
            accA[j].y += __shfl_xor(accA[j].y, 32);
        }
        if (q == 0) {
            uint4 o;
            o.x = pack2(accA[0].x, accA[0].y);
            o.y = pack2(accA[1].x, accA[1].y);
            o.z = pack2(accA[2].x, accA[2].y);
            o.w = pack2(accA[3].x, accA[3].y);
            *(uint4*)(sA + tl * 136 + sl * 8) = o;
        }
    }
    __syncthreads();

    const int wr    = (w & 3) * 16;
    const int cbase = (w >> 2) * 4;
    const int fr    = lane & 15;
    const int fq    = lane >> 4;

    f32x4 acc[4];
    #pragma unroll
    for (int cf = 0; cf < 4; ++cf) acc[cf] = (f32x4){0.f, 0.f, 0.f, 0.f};

    #pragma unroll
    for (int ks = 0; ks < 4; ++ks) {
        const bf16x8 a = *(const bf16x8*)(sA + (wr + fr) * 136 + ks * 32 + fq * 8);
        #pragma unroll
        for (int cf = 0; cf < 4; ++cf) {
            const bf16x8 b = *(const bf16x8*)(sB + ((cbase + cf) * 16 + fr) * 136 + ks * 32 + fq * 8);
            acc[cf] = __builtin_amdgcn_mfma_f32_16x16x32_bf16(a, b, acc[cf], 0, 0, 0);
        }
    }
    __syncthreads();

    #pragma unroll
    for (int cf = 0; cf < 4; ++cf) {
        #pragma unroll
        for (int j = 0; j < 4; ++j) {
            const int row = wr + fq * 4 + j;
            sA[row * 136 + (cbase + cf) * 16 + fr] = f2bf(acc[cf][j]);
        }
    }
    __syncthreads();

    #pragma unroll
    for (int i = 0; i < 2; ++i) {
        const int f = tid + i * 512;
        const int row = f >> 4, unit = f & 15;
        const int t = tile * TILE_T + row;
        if (t < TNODE)
            *(uint4*)(P + ((size_t)r * TNODE + t) * C + unit * 8) =
                *(const uint4*)(sA + row * 136 + unit * 8);
    }
}

// ---------------- tier-3 fallback: round-1 fused (no workspace) ----------------
__device__ __forceinline__ void add4(float4& acc, const float4& b) {
    acc.x += b.x; acc.y += b.y; acc.z += b.z; acc.w += b.w;
}
__global__ __launch_bounds__(256, 1)
void rgcn_fused_kernel(const float* __restrict__ x, const float* __restrict__ w,
                       const int* __restrict__ ptr, const int* __restrict__ idx,
                       const int* __restrict__ tgt, float* __restrict__ out) {
    __shared__ float sW[C * C];
    __shared__ float sAgg[TILE_T][C + 4];
    const int tid = threadIdx.x, tile = blockIdx.x, r = blockIdx.y;
    {
        const float4* src = (const float4*)(w + (size_t)r * C * C);
        float4* dst = (float4*)sW;
        #pragma unroll
        for (int i = 0; i < 16; ++i) dst[tid + i * 256] = src[tid + i * 256];
    }
    {
        const int tl = tid >> 2, g = tid & 3;
        const int t = tile * TILE_T + tl;
        float4 a[8];
        #pragma unroll
        for (int j = 0; j < 8; ++j) a[j] = make_float4(0.f, 0.f, 0.f, 0.f);
        if (t < TNODE) {
            const int* pr = ptr + (size_t)r * (TNODE + 1);
            const int* er = idx + (size_t)r * NEDGE;
            int e = (t == 0) ? 0 : pr[t];
            const int end = (t == TNODE - 1) ? NEDGE : pr[t + 1];
            for (; e < end; ++e) {
                const int s0 = er[e];
                const float4* r0 = (const float4*)(x + (size_t)s0 * C) + g * 8;
                #pragma unroll
                for (int j = 0; j < 8; ++j) add4(a[j], r0[j]);
            }
        }
        float* rowp = &sAgg[tl][g * 32];
        #pragma unroll
        for (int j = 0; j < 8; ++j) ((float4*)rowp)[j] = a[j];
    }
    __syncthreads();
    const int tg = tid >> 4, cg = tid & 15;
    float4 acc0[4], acc1[4];
    #pragma unroll
    for (int i = 0; i < 4; ++i) {
        acc0[i] = make_float4(0.f, 0.f, 0.f, 0.f);
        acc1[i] = make_float4(0.f, 0.f, 0.f, 0.f);
    }
    for (int k4 = 0; k4 < C / 4; ++k4) {
        float4 av[4];
        #pragma unroll
        for (int i = 0; i < 4; ++i) av[i] = *(const float4*)&sAgg[tg * 4 + i][k4 * 4];
        #pragma unroll
        for (int kk = 0; kk < 4; ++kk) {
            const int k = k4 * 4 + kk;
            const float4 w0 = *(const float4*)&sW[k * C + cg * 4];
            const float4 w1 = *(const float4*)&sW[k * C + 64 + cg * 4];
            #pragma unroll
            for (int i = 0; i < 4; ++i) {
                const float a = ((const float*)&av[i])[kk];
                fma4(acc0[i], a, w0.x, w0.y, w0.z, w0.w);
                fma4(acc1[i], a, w1.x, w1.y, w1.z, w1.w);
            }
        }
    }
    const int* tr = tgt + (size_t)r * TNODE;
    #pragma unroll
    for (int i = 0; i < 4; ++i) {
        const int t = tile * TILE_T + tg * 4 + i;
        if (t < TNODE) {
            const int node = tr[t];
            float* ob = out + (size_t)node * C + cg * 4;
            unsafeAtomicAdd(ob + 0, acc0[i].x);  unsafeAtomicAdd(ob + 1, acc0[i].y);
            unsafeAtomicAdd(ob + 2, acc0[i].z);  unsafeAtomicAdd(ob + 3, acc0[i].w);
            unsafeAtomicAdd(ob + 64, acc1[i].x); unsafeAtomicAdd(ob + 65, acc1[i].y);
            unsafeAtomicAdd(ob + 66, acc1[i].z); unsafeAtomicAdd(ob + 67, acc1[i].w);
        }
    }
}

extern "C" void kernel_launch(void* const* d_in, const int* in_sizes, int n_in,
                              void* d_out, int out_size, void* d_ws, size_t ws_size,
                              hipStream_t stream) {
    const float* x   = (const float*)d_in[0];
    const float* w   = (const float*)d_in[1];
    const int*   ptr = (const int*)d_in[2];
    const int*   idx = (const int*)d_in[3];
    const int*   tgt = (const int*)d_in[4];
    float* out = (float*)d_out;

    // ---- tier-1 layout (233.5 MB) ----
    const size_t P_OFF    = 0;                       // 102,400,000
    const size_t AGGS_OFF = 102400000;               // 102,400,000
    const size_t XBS_OFF  = 204800000;               //  25,600,000
    const size_t WTB_OFF  = 230400000;               //     262,144
    const size_t CNT_OFF  = 230662144;
    const size_t OFFS_OFF = 231062144;
    const size_t CUR_OFF  = 231462144;
    const size_t BSUM_OFF = 231862144;
    const size_t LIST_OFF = 231864192;
    const size_t WS_T1    = 233464192;
    // ---- tier-2 layout (135 MB, round-8 proven) ----
    const size_t WS_T2    = 135000000;

    char* base = (char*)d_ws;

    if (ws_size >= WS_T1) {
        u16* P       = (u16*)(base + P_OFF);
        u16* aggS    = (u16*)(base + AGGS_OFF);
        u16* xbS     = (u16*)(base + XBS_OFF);
        u16* wtb     = (u16*)(base + WTB_OFF);
        int* count   = (int*)(base + CNT_OFF);
        int* offsets = (int*)(base + OFFS_OFF);
        int* cursor  = (int*)(base + CUR_OFF);
        int* bsum    = (int*)(base + BSUM_OFF);
        int* list    = (int*)(base + LIST_OFF);

        convert_x_shard_kernel<<<(NSHARD * NNODE + 255) / 256, 256, 0, stream>>>(x, xbS);
        convert_w_kernel<<<(NREL * C * C + 255) / 256, 256, 0, stream>>>(w, wtb);

        hipMemsetAsync(count, 0, NNODE * sizeof(int), stream);
        hist_kernel<<<(NENT + 255) / 256, 256, 0, stream>>>(tgt, count);
        scan1_kernel<<<NB_SCAN, 256, 0, stream>>>(count, bsum);
        scan2_kernel<<<1, 512, 0, stream>>>(bsum);
        scan3_kernel<<<NB_SCAN, 256, 0, stream>>>(count, bsum, offsets, cursor);
        fill_kernel<<<(NENT + 255) / 256, 256, 0, stream>>>(tgt, cursor, list);

        gather_shard_kernel<<<NTILE * NREL * NSHARD, 256, 0, stream>>>(xbS, ptr, idx, aggS);

        dim3 grid(NTILE, NREL);
        gemm_mfma_kernel<<<grid, 256, 0, stream>>>(aggS, wtb, P);

        out_gather_kernel<<<(NNODE + 3) / 4, 256, 0, stream>>>(P, offsets, count, list, out);
    } else if (ws_size >= WS_T2) {
        u16* P       = (u16*)(base + 0);
        u16* xb      = (u16*)(base + 104000000);
        u16* wtb     = (u16*)(base + 130000000);
        int* count   = (int*)(base + 131000000);
        int* offsets = (int*)(base + 131500000);
        int* cursor  = (int*)(base + 132000000);
        int* bsum    = (int*)(base + 132500000);
        int* list    = (int*)(base + 133000000);

        convert_x_kernel<<<2048, 256, 0, stream>>>(x, xb, NNODE * C / 4);
        convert_w_kernel<<<(NREL * C * C + 255) / 256, 256, 0, stream>>>(w, wtb);

        hipMemsetAsync(count, 0, NNODE * sizeof(int), stream);
        hist_kernel<<<(NENT + 255) / 256, 256, 0, stream>>>(tgt, count);
        scan1_kernel<<<NB_SCAN, 256, 0, stream>>>(count, bsum);
        scan2_kernel<<<1, 512, 0, stream>>>(bsum);
        scan3_kernel<<<NB_SCAN, 256, 0, stream>>>(count, bsum, offsets, cursor);
        fill_kernel<<<(NENT + 255) / 256, 256, 0, stream>>>(tgt, cursor, list);

        dim3 grid(NTILE, NREL);
        fused_gather_gemm_kernel<<<grid, 512, 0, stream>>>(xb, ptr, idx, wtb, P);

        out_gather_kernel<<<(NNODE + 3) / 4, 256, 0, stream>>>(P, offsets, count, list, out);
    } else {
        hipMemsetAsync(out, 0, (size_t)NNODE * C * sizeof(float), stream);
        dim3 grid(NTILE, NREL);
        rgcn_fused_kernel<<<grid, 256, 0, stream>>>(x, w, ptr, idx, tgt, out);
    }
}

// Round 14
// 368.093 us; speedup vs baseline: 1.8580x; 1.8580x over previous
//
#include <hip/hip_runtime.h>

#define NREL 8
#define NNODE 100000
#define TNODE 50000
#define NEDGE 800000
#define C 128
#define TILE_T 64
#define NTILE ((TNODE + TILE_T - 1) / TILE_T)   // 782
#define NENT (NREL * TNODE)                     // 400000
#define NB_SCAN ((NNODE + 255) / 256)           // 391

typedef unsigned int u32;
typedef unsigned short u16;
typedef __attribute__((ext_vector_type(8))) short bf16x8;
typedef __attribute__((ext_vector_type(4))) float f32x4;
typedef __attribute__((ext_vector_type(2))) float f32x2;

__device__ __forceinline__ u16 f2bf(float f) {
    union { float f; u32 u; } c; c.f = f;
    u32 u = c.u + 0x7FFFu + ((c.u >> 16) & 1u);   // RNE
    return (u16)(u >> 16);
}
__device__ __forceinline__ u32 pack2(float a, float b) {
    return (u32)f2bf(a) | ((u32)f2bf(b) << 16);
}
__device__ __forceinline__ float2 unpack_bf2(u32 p) {
    union { u32 u; float f; } a, b;
    a.u = p << 16; b.u = p & 0xFFFF0000u;
    return make_float2(a.f, b.f);
}
__device__ __forceinline__ f32x2 bits2(u32 p) {
    union { u32 u[2]; f32x2 f; } c;
    c.u[0] = p << 16; c.u[1] = p & 0xFFFF0000u;
    return c.f;
}
__device__ __forceinline__ void addp(f32x2* a, uint4 v) {
    a[0] += bits2(v.x); a[1] += bits2(v.y);
    a[2] += bits2(v.z); a[3] += bits2(v.w);
}
__device__ __forceinline__ void fma4(float4& acc, float a, float w0, float w1, float w2, float w3) {
    acc.x = fmaf(a, w0, acc.x);
    acc.y = fmaf(a, w1, acc.y);
    acc.z = fmaf(a, w2, acc.z);
    acc.w = fmaf(a, w3, acc.w);
}

// ---------------- kernel 1a: x f32 -> bf16 (row-major) ----------------
__global__ __launch_bounds__(256)
void convert_x_kernel(const float* __restrict__ x, u16* __restrict__ xb, int n4) {
    int i = blockIdx.x * 256 + threadIdx.x;
    const int stride = gridDim.x * 256;
    for (; i < n4; i += stride) {
        const float4 v = ((const float4*)x)[i];
        ushort4 o;
        o.x = f2bf(v.x); o.y = f2bf(v.y); o.z = f2bf(v.z); o.w = f2bf(v.w);
        ((ushort4*)xb)[i] = o;
    }
}

// ---------------- kernel 1b: W f32 [r][k][c] -> bf16 W^T [r][c][k] ----------------
__global__ __launch_bounds__(256)
void convert_w_kernel(const float* __restrict__ w, u16* __restrict__ wtb) {
    const int o = blockIdx.x * 256 + threadIdx.x;
    if (o < NREL * C * C) {
        const int r = o >> 14, rem = o & 16383, cc = rem >> 7, k = rem & 127;
        wtb[o] = f2bf(w[(r << 14) + k * C + cc]);
    }
}

// ---------------- inverted-index build (scan3 folded into fill/out_gather) ----------------
__global__ __launch_bounds__(256)
void hist_kernel(const int* __restrict__ tgt, int* __restrict__ count) {
    const int g = blockIdx.x * 256 + threadIdx.x;
    if (g < NENT) atomicAdd(&count[tgt[g]], 1);
}

// per-block local exclusive prefix -> offsets & cursor; block total -> bsum
__global__ __launch_bounds__(256)
void scan1_kernel(const int* __restrict__ count, int* __restrict__ bsum,
                  int* __restrict__ offsets, int* __restrict__ cursor) {
    __shared__ int s[256];
    const int tid = threadIdx.x;
    const int i = blockIdx.x * 256 + tid;
    const int v = (i < NNODE) ? count[i] : 0;
    s[tid] = v;
    __syncthreads();
    for (int st = 1; st < 256; st <<= 1) {
        const int t = (tid >= st) ? s[tid - st] : 0;
        __syncthreads();
        s[tid] += t;
        __syncthreads();
    }
    if (i < NNODE) {
        const int loc = s[tid] - v;   // local exclusive
        offsets[i] = loc;
        cursor[i]  = loc;
    }
    if (tid == 255) bsum[blockIdx.x] = s[255];
}

__global__ __launch_bounds__(512)
void scan2_kernel(int* __restrict__ bsum) {   // exclusive scan of NB_SCAN partials
    __shared__ int s[512];
    const int tid = threadIdx.x;
    const int v = (tid < NB_SCAN) ? bsum[tid] : 0;
    s[tid] = v;
    __syncthreads();
    for (int st = 1; st < 512; st <<= 1) {
        const int t = (tid >= st) ? s[tid - st] : 0;
        __syncthreads();
        s[tid] += t;
        __syncthreads();
    }
    if (tid < NB_SCAN) bsum[tid] = s[tid] - v;
}

__global__ __launch_bounds__(256)
void fill_kernel(const int* __restrict__ tgt, int* __restrict__ cursor,
                 const int* __restrict__ bsum, int* __restrict__ list) {
    const int g = blockIdx.x * 256 + threadIdx.x;
    if (g < NENT) {
        const int t = tgt[g];
        const int pos = atomicAdd(&cursor[t], 1) + bsum[t >> 8];
        list[pos] = g;
    }
}

// ---------------- kernel 2: FUSED gather-sum + MFMA GEMM (B from global) ----------------
// Block = (64-target tile, relation r). 8 waves x 64 lanes. LDS = sA only (~17.5 KB)
// -> 4 blocks/CU = 8 waves/SIMD. GEMM B-fragments load straight from wtb (L2-hot).
__global__ __launch_bounds__(512, 8)
void fused_gather_gemm_kernel(const u16* __restrict__ xb, const int* __restrict__ ptr,
                              const int* __restrict__ idx, const u16* __restrict__ wtb,
                              u16* __restrict__ P) {
    __shared__ u16 sA[TILE_T * 136];   // 17408 B: agg tile -> output tile
    __shared__ int qcount;             // dynamic target ticket

    const int tid  = threadIdx.x;
    const int tile = blockIdx.x;
    const int r    = blockIdx.y;
    const int w    = tid >> 6;
    const int lane = tid & 63;

    if (tid == 0) qcount = 0;
    __syncthreads();

    // ---- phase 1: dynamic gather, one target per queue pop ----
    const int* pr = ptr + r * (TNODE + 1);
    const int* er = idx + (size_t)r * NEDGE;
    const int q  = lane >> 4;    // edge slot 0..3
    const int sl = lane & 15;    // 8-col chunk (16B)
    const u16* xcol = xb + sl * 8;

    for (;;) {
        int tl;
        if (lane == 0) tl = atomicAdd(&qcount, 1);
        tl = __shfl(tl, 0);
        if (tl >= TILE_T) break;

        const int t = tile * TILE_T + tl;
        f32x2 accA[4], accB[4];
        #pragma unroll
        for (int j = 0; j < 4; ++j) { accA[j] = (f32x2){0.f, 0.f}; accB[j] = (f32x2){0.f, 0.f}; }

        if (t < TNODE) {
            // clip(searchsorted(ptr,e,'right')-1, 0, T-1):
            //   t==0 owns [0, ptr[1]); t==T-1 owns [ptr[T-1], E)
            const int start = (t == 0) ? 0 : pr[t];
            const int end   = (t == TNODE - 1) ? NEDGE : pr[t + 1];

            for (int base = start; base < end; base += 64) {
                const int cnt = min(end - base, 64);
                int myi = (lane < cnt) ? er[base + lane] : 0;
                int i = 0;
                for (; i + 8 <= cnt; i += 8) {           // 8 edges/iter, 2 loads in flight/lane
                    const int sA0 = __shfl(myi, i + q);
                    const int sB0 = __shfl(myi, i + 4 + q);
                    const uint4 vA = *(const uint4*)(xcol + (size_t)sA0 * C);
                    const uint4 vB = *(const uint4*)(xcol + (size_t)sB0 * C);
                    addp(accA, vA);
                    addp(accB, vB);
                }
                if (i + 4 <= cnt) {
                    const int sA0 = __shfl(myi, i + q);
                    const uint4 vA = *(const uint4*)(xcol + (size_t)sA0 * C);
                    addp(accA, vA);
                    i += 4;
                }
                if (i < cnt) {
                    const int rem = cnt - i;
                    const int sA0 = __shfl(myi, i + ((q < rem) ? q : 0));
                    if (q < rem) {
                        const uint4 vA = *(const uint4*)(xcol + (size_t)sA0 * C);
                        addp(accA, vA);
                    }
                }
            }
        }
        #pragma unroll
        for (int j = 0; j < 4; ++j) {
            accA[j] += accB[j];
            accA[j].x += __shfl_xor(accA[j].x, 16);
            accA[j].y += __shfl_xor(accA[j].y, 16);
            accA[j].x += __shfl_xor(accA[j].x, 32);
            accA[j].y += __shfl_xor(accA[j].y, 32);
        }
        if (q == 0) {
            uint4 o;
            o.x = pack2(accA[0].x, accA[0].y);
            o.y = pack2(accA[1].x, accA[1].y);
            o.z = pack2(accA[2].x, accA[2].y);
            o.w = pack2(accA[3].x, accA[3].y);
            *(uint4*)(sA + tl * 136 + sl * 8) = o;
        }
    }
    __syncthreads();

    // ---- phase 2: MFMA GEMM, B-fragments direct from global wtb (L2-hot, 782x reuse) ----
    const int wr    = (w & 3) * 16;
    const int cbase = (w >> 2) * 4;
    const int fr    = lane & 15;
    const int fq    = lane >> 4;
    const u16* wb   = wtb + (size_t)r * C * C;

    f32x4 acc[4];
    #pragma unroll
    for (int cf = 0; cf < 4; ++cf) acc[cf] = (f32x4){0.f, 0.f, 0.f, 0.f};

    #pragma unroll
    for (int ks = 0; ks < 4; ++ks) {
        const bf16x8 a = *(const bf16x8*)(sA + (wr + fr) * 136 + ks * 32 + fq * 8);
        #pragma unroll
        for (int cf = 0; cf < 4; ++cf) {
            const bf16x8 b = *(const bf16x8*)(wb + ((cbase + cf) * 16 + fr) * C + ks * 32 + fq * 8);
            acc[cf] = __builtin_amdgcn_mfma_f32_16x16x32_bf16(a, b, acc[cf], 0, 0, 0);
        }
    }
    __syncthreads();   // all A-frag reads done before D overwrites sA

    // D -> sA as bf16 (C/D layout: col=lane&15, row=(lane>>4)*4+reg)
    #pragma unroll
    for (int cf = 0; cf < 4; ++cf) {
        #pragma unroll
        for (int j = 0; j < 4; ++j) {
            const int row = wr + fq * 4 + j;
            sA[row * 136 + (cbase + cf) * 16 + fr] = f2bf(acc[cf][j]);
        }
    }
    __syncthreads();

    // coalesced store into P
    #pragma unroll
    for (int i = 0; i < 2; ++i) {
        const int f = tid + i * 512;
        const int row = f >> 4, unit = f & 15;
        const int t = tile * TILE_T + row;
        if (t < TNODE)
            *(uint4*)(P + ((size_t)r * TNODE + t) * C + unit * 8) =
                *(const uint4*)(sA + row * 136 + unit * 8);
    }
}

// ---------------- kernel 3: per-node gather of bf16 arr rows (no atomics) ----------------
__global__ __launch_bounds__(256)
void out_gather_kernel(const u16* __restrict__ P, const int* __restrict__ offsets,
                       const int* __restrict__ count, const int* __restrict__ bsum,
                       const int* __restrict__ list, float* __restrict__ out) {
    const int lane = threadIdx.x & 63;
    const int n = blockIdx.x * 4 + (threadIdx.x >> 6);
    if (n >= NNODE) return;
    const int st = offsets[n] + bsum[n >> 8];
    const int en = st + count[n];
    float2 a0 = make_float2(0.f, 0.f), a1 = make_float2(0.f, 0.f);
    int i = st;
    for (; i + 2 <= en; i += 2) {
        const u32 v0 = ((const u32*)(P + (size_t)list[i] * C))[lane];
        const u32 v1 = ((const u32*)(P + (size_t)list[i + 1] * C))[lane];
        const float2 f0 = unpack_bf2(v0), f1 = unpack_bf2(v1);
        a0.x += f0.x; a0.y += f0.y;
        a1.x += f1.x; a1.y += f1.y;
    }
    if (i < en) {
        const float2 f0 = unpack_bf2(((const u32*)(P + (size_t)list[i] * C))[lane]);
        a0.x += f0.x; a0.y += f0.y;
    }
    a0.x += a1.x; a0.y += a1.y;
    ((float2*)(out + (size_t)n * C))[lane] = a0;
}

// ---------------- fallback: round-1 fused (no workspace) ----------------
__device__ __forceinline__ void add4(float4& acc, const float4& b) {
    acc.x += b.x; acc.y += b.y; acc.z += b.z; acc.w += b.w;
}
__global__ __launch_bounds__(256, 1)
void rgcn_fused_kernel(const float* __restrict__ x, const float* __restrict__ w,
                       const int* __restrict__ ptr, const int* __restrict__ idx,
                       const int* __restrict__ tgt, float* __restrict__ out) {
    __shared__ float sW[C * C];
    __shared__ float sAgg[TILE_T][C + 4];
    const int tid = threadIdx.x, tile = blockIdx.x, r = blockIdx.y;
    {
        const float4* src = (const float4*)(w + (size_t)r * C * C);
        float4* dst = (float4*)sW;
        #pragma unroll
        for (int i = 0; i < 16; ++i) dst[tid + i * 256] = src[tid + i * 256];
    }
    {
        const int tl = tid >> 2, g = tid & 3;
        const int t = tile * TILE_T + tl;
        float4 a[8];
        #pragma unroll
        for (int j = 0; j < 8; ++j) a[j] = make_float4(0.f, 0.f, 0.f, 0.f);
        if (t < TNODE) {
            const int* pr = ptr + (size_t)r * (TNODE + 1);
            const int* er = idx + (size_t)r * NEDGE;
            int e = (t == 0) ? 0 : pr[t];
            const int end = (t == TNODE - 1) ? NEDGE : pr[t + 1];
            for (; e < end; ++e) {
                const int s0 = er[e];
                const float4* r0 = (const float4*)(x + (size_t)s0 * C) + g * 8;
                #pragma unroll
                for (int j = 0; j < 8; ++j) add4(a[j], r0[j]);
            }
        }
        float* rowp = &sAgg[tl][g * 32];
        #pragma unroll
        for (int j = 0; j < 8; ++j) ((float4*)rowp)[j] = a[j];
    }
    __syncthreads();
    const int tg = tid >> 4, cg = tid & 15;
    float4 acc0[4], acc1[4];
    #pragma unroll
    for (int i = 0; i < 4; ++i) {
        acc0[i] = make_float4(0.f, 0.f, 0.f, 0.f);
        acc1[i] = make_float4(0.f, 0.f, 0.f, 0.f);
    }
    for (int k4 = 0; k4 < C / 4; ++k4) {
        float4 av[4];
        #pragma unroll
        for (int i = 0; i < 4; ++i) av[i] = *(const float4*)&sAgg[tg * 4 + i][k4 * 4];
        #pragma unroll
        for (int kk = 0; kk < 4; ++kk) {
            const int k = k4 * 4 + kk;
            const float4 w0 = *(const float4*)&sW[k * C + cg * 4];
            const float4 w1 = *(const float4*)&sW[k * C + 64 + cg * 4];
            #pragma unroll
            for (int i = 0; i < 4; ++i) {
                const float a = ((const float*)&av[i])[kk];
                fma4(acc0[i], a, w0.x, w0.y, w0.z, w0.w);
                fma4(acc1[i], a, w1.x, w1.y, w1.z, w1.w);
            }
        }
    }
    const int* tr = tgt + (size_t)r * TNODE;
    #pragma unroll
    for (int i = 0; i < 4; ++i) {
        const int t = tile * TILE_T + tg * 4 + i;
        if (t < TNODE) {
            const int node = tr[t];
            float* ob = out + (size_t)node * C + cg * 4;
            unsafeAtomicAdd(ob + 0, acc0[i].x);  unsafeAtomicAdd(ob + 1, acc0[i].y);
            unsafeAtomicAdd(ob + 2, acc0[i].z);  unsafeAtomicAdd(ob + 3, acc0[i].w);
            unsafeAtomicAdd(ob + 64, acc1[i].x); unsafeAtomicAdd(ob + 65, acc1[i].y);
            unsafeAtomicAdd(ob + 66, acc1[i].z); unsafeAtomicAdd(ob + 67, acc1[i].w);
        }
    }
}

extern "C" void kernel_launch(void* const* d_in, const int* in_sizes, int n_in,
                              void* d_out, int out_size, void* d_ws, size_t ws_size,
                              hipStream_t stream) {
    const float* x   = (const float*)d_in[0];
    const float* w   = (const float*)d_in[1];
    const int*   ptr = (const int*)d_in[2];
    const int*   idx = (const int*)d_in[3];
    const int*   tgt = (const int*)d_in[4];
    float* out = (float*)d_out;

    // workspace layout (135 MB, round-8 proven)
    const size_t WS_NEED = 135000000;
    char* base = (char*)d_ws;

    if (ws_size >= WS_NEED) {
        u16* P       = (u16*)(base + 0);          // 102.4 MB
        u16* xb      = (u16*)(base + 104000000);  //  25.6 MB
        u16* wtb     = (u16*)(base + 130000000);  //  0.26 MB
        int* count   = (int*)(base + 131000000);
        int* offsets = (int*)(base + 131500000);
        int* cursor  = (int*)(base + 132000000);
        int* bsum    = (int*)(base + 132500000);
        int* list    = (int*)(base + 133000000);  // 1.6 MB

        convert_x_kernel<<<2048, 256, 0, stream>>>(x, xb, NNODE * C / 4);
        convert_w_kernel<<<(NREL * C * C + 255) / 256, 256, 0, stream>>>(w, wtb);

        hipMemsetAsync(count, 0, NNODE * sizeof(int), stream);
        hist_kernel<<<(NENT + 255) / 256, 256, 0, stream>>>(tgt, count);
        scan1_kernel<<<NB_SCAN, 256, 0, stream>>>(count, bsum, offsets, cursor);
        scan2_kernel<<<1, 512, 0, stream>>>(bsum);
        fill_kernel<<<(NENT + 255) / 256, 256, 0, stream>>>(tgt, cursor, bsum, list);

        dim3 grid(NTILE, NREL);
        fused_gather_gemm_kernel<<<grid, 512, 0, stream>>>(xb, ptr, idx, wtb, P);

        out_gather_kernel<<<(NNODE + 3) / 4, 256, 0, stream>>>(P, offsets, count, bsum, list, out);
    } else {
        hipMemsetAsync(out, 0, (size_t)NNODE * C * sizeof(float), stream);
        dim3 grid(NTILE, NREL);
        rgcn_fused_kernel<<<grid, 256, 0, stream>>>(x, w, ptr, idx, tgt, out);
    }
}

// Round 16
// 339.918 us; speedup vs baseline: 2.0120x; 1.0829x over previous
//
#include <hip/hip_runtime.h>

#define NREL 8
#define NNODE 100000
#define TNODE 50000
#define NEDGE 800000
#define C 128
#define TILE_T 64
#define NTILE ((TNODE + TILE_T - 1) / TILE_T)   // 782
#define NENT (NREL * TNODE)                     // 400000
#define NB_SCAN ((NNODE + 255) / 256)           // 391

// setup kernel block partition
#define NB_CVX (NNODE * C / 4 / 256)            // 12500
#define NB_CVW (NREL * C * C / 256)             // 512
#define NB_ZERO NB_SCAN                         // 391

typedef unsigned int u32;
typedef unsigned short u16;
typedef __attribute__((ext_vector_type(8))) short bf16x8;
typedef __attribute__((ext_vector_type(4))) float f32x4;
typedef __attribute__((ext_vector_type(2))) float f32x2;

__device__ __forceinline__ u16 f2bf(float f) {
    union { float f; u32 u; } c; c.f = f;
    u32 u = c.u + 0x7FFFu + ((c.u >> 16) & 1u);   // RNE
    return (u16)(u >> 16);
}
__device__ __forceinline__ u32 pack2(float a, float b) {
    return (u32)f2bf(a) | ((u32)f2bf(b) << 16);
}
__device__ __forceinline__ float2 unpack_bf2(u32 p) {
    union { u32 u; float f; } a, b;
    a.u = p << 16; b.u = p & 0xFFFF0000u;
    return make_float2(a.f, b.f);
}
__device__ __forceinline__ f32x2 bits2(u32 p) {
    union { u32 u[2]; f32x2 f; } c;
    c.u[0] = p << 16; c.u[1] = p & 0xFFFF0000u;
    return c.f;
}
__device__ __forceinline__ void addp(f32x2* a, uint4 v) {
    a[0] += bits2(v.x); a[1] += bits2(v.y);
    a[2] += bits2(v.z); a[3] += bits2(v.w);
}
__device__ __forceinline__ void fma4(float4& acc, float a, float w0, float w1, float w2, float w3) {
    acc.x = fmaf(a, w0, acc.x);
    acc.y = fmaf(a, w1, acc.y);
    acc.z = fmaf(a, w2, acc.z);
    acc.w = fmaf(a, w3, acc.w);
}

// ---------------- kernel 1: consolidated setup ----------------
// blocks [0, NB_CVX):            x f32 -> bf16 row-major
// blocks [NB_CVX, +NB_CVW):      W f32 [r][k][c] -> bf16 W^T [r][c][k]
// blocks [NB_CVX+NB_CVW, +391):  zero count[]
__global__ __launch_bounds__(256)
void setup_kernel(const float* __restrict__ x, u16* __restrict__ xb,
                  const float* __restrict__ w, u16* __restrict__ wtb,
                  int* __restrict__ count) {
    const int b = blockIdx.x;
    const int tid = threadIdx.x;
    if (b < NB_CVX) {
        const int i = b * 256 + tid;             // < 3.2M units, exact
        const float4 v = ((const float4*)x)[i];
        ushort4 o;
        o.x = f2bf(v.x); o.y = f2bf(v.y); o.z = f2bf(v.z); o.w = f2bf(v.w);
        ((ushort4*)xb)[i] = o;
    } else if (b < NB_CVX + NB_CVW) {
        const int o = (b - NB_CVX) * 256 + tid;  // < 131072, exact
        const int r = o >> 14, rem = o & 16383, cc = rem >> 7, k = rem & 127;
        wtb[o] = f2bf(w[(r << 14) + k * C + cc]);
    } else {
        const int i = (b - NB_CVX - NB_CVW) * 256 + tid;
        if (i < NNODE) count[i] = 0;
    }
}

// ---------------- inverted-index build ----------------
__global__ __launch_bounds__(256)
void hist_kernel(const int* __restrict__ tgt, int* __restrict__ count) {
    const int g = blockIdx.x * 256 + threadIdx.x;
    if (g < NENT) atomicAdd(&count[tgt[g]], 1);
}

// per-block local exclusive prefix -> offsets & cursor; block total -> bsum
__global__ __launch_bounds__(256)
void scan1_kernel(const int* __restrict__ count, int* __restrict__ bsum,
                  int* __restrict__ offsets, int* __restrict__ cursor) {
    __shared__ int s[256];
    const int tid = threadIdx.x;
    const int i = blockIdx.x * 256 + tid;
    const int v = (i < NNODE) ? count[i] : 0;
    s[tid] = v;
    __syncthreads();
    for (int st = 1; st < 256; st <<= 1) {
        const int t = (tid >= st) ? s[tid - st] : 0;
        __syncthreads();
        s[tid] += t;
        __syncthreads();
    }
    if (i < NNODE) {
        const int loc = s[tid] - v;   // local exclusive
        offsets[i] = loc;
        cursor[i]  = loc;
    }
    if (tid == 255) bsum[blockIdx.x] = s[255];
}

__global__ __launch_bounds__(512)
void scan2_kernel(int* __restrict__ bsum) {   // exclusive scan of NB_SCAN partials
    __shared__ int s[512];
    const int tid = threadIdx.x;
    const int v = (tid < NB_SCAN) ? bsum[tid] : 0;
    s[tid] = v;
    __syncthreads();
    for (int st = 1; st < 512; st <<= 1) {
        const int t = (tid >= st) ? s[tid - st] : 0;
        __syncthreads();
        s[tid] += t;
        __syncthreads();
    }
    if (tid < NB_SCAN) bsum[tid] = s[tid] - v;
}

__global__ __launch_bounds__(256)
void fill_kernel(const int* __restrict__ tgt, int* __restrict__ cursor,
                 const int* __restrict__ bsum, int* __restrict__ list) {
    const int g = blockIdx.x * 256 + threadIdx.x;
    if (g < NENT) {
        const int t = tgt[g];
        const int pos = atomicAdd(&cursor[t], 1) + bsum[t >> 8];
        list[pos] = g;
    }
}

// ---------------- kernel 2: FUSED gather-sum + MFMA GEMM (round-8 proven config) ----------------
// Block = (64-target tile, relation r). 8 waves x 64 lanes. sB (W^T) staged in LDS.
__global__ __launch_bounds__(512, 6)
void fused_gather_gemm_kernel(const u16* __restrict__ xb, const int* __restrict__ ptr,
                              const int* __restrict__ idx, const u16* __restrict__ wtb,
                              u16* __restrict__ P) {
    __shared__ u16 sB[C * 136];        // 34816 B: W^T [col][k+pad]
    __shared__ u16 sA[TILE_T * 136];   // 17408 B: agg tile -> output tile
    __shared__ int qcount;             // dynamic target ticket

    const int tid  = threadIdx.x;
    const int tile = blockIdx.x;
    const int r    = blockIdx.y;
    const int w    = tid >> 6;
    const int lane = tid & 63;

    // ---- stage W^T into sB (overlaps gather; pre-GEMM barrier covers it) ----
    {
        const uint4* src = (const uint4*)(wtb + (size_t)r * C * C);
        #pragma unroll
        for (int i = 0; i < 4; ++i) {
            const int f = tid + i * 512;        // 2048 16B-units
            const int col = f >> 4, unit = f & 15;
            *(uint4*)(sB + col * 136 + unit * 8) = src[f];
        }
    }
    if (tid == 0) qcount = 0;
    __syncthreads();

    // ---- phase 1: dynamic gather, one target per queue pop ----
    const int* pr = ptr + r * (TNODE + 1);
    const int* er = idx + (size_t)r * NEDGE;
    const int q  = lane >> 4;    // edge slot 0..3
    const int sl = lane & 15;    // 8-col chunk (16B)
    const u16* xcol = xb + sl * 8;

    for (;;) {
        int tl;
        if (lane == 0) tl = atomicAdd(&qcount, 1);
        tl = __shfl(tl, 0);
        if (tl >= TILE_T) break;

        const int t = tile * TILE_T + tl;
        f32x2 accA[4], accB[4];
        #pragma unroll
        for (int j = 0; j < 4; ++j) { accA[j] = (f32x2){0.f, 0.f}; accB[j] = (f32x2){0.f, 0.f}; }

        if (t < TNODE) {
            // clip(searchsorted(ptr,e,'right')-1, 0, T-1):
            //   t==0 owns [0, ptr[1]); t==T-1 owns [ptr[T-1], E)
            const int start = (t == 0) ? 0 : pr[t];
            const int end   = (t == TNODE - 1) ? NEDGE : pr[t + 1];

            for (int base = start; base < end; base += 64) {
                const int cnt = min(end - base, 64);
                int myi = (lane < cnt) ? er[base + lane] : 0;
                int i = 0;
                for (; i + 8 <= cnt; i += 8) {           // 8 edges/iter, 2 loads in flight/lane
                    const int sA0 = __shfl(myi, i + q);
                    const int sB0 = __shfl(myi, i + 4 + q);
                    const uint4 vA = *(const uint4*)(xcol + (size_t)sA0 * C);
                    const uint4 vB = *(const uint4*)(xcol + (size_t)sB0 * C);
                    addp(accA, vA);
                    addp(accB, vB);
                }
                if (i + 4 <= cnt) {
                    const int sA0 = __shfl(myi, i + q);
                    const uint4 vA = *(const uint4*)(xcol + (size_t)sA0 * C);
                    addp(accA, vA);
                    i += 4;
                }
                if (i < cnt) {
                    const int rem = cnt - i;
                    const int sA0 = __shfl(myi, i + ((q < rem) ? q : 0));
                    if (q < rem) {
                        const uint4 vA = *(const uint4*)(xcol + (size_t)sA0 * C);
                        addp(accA, vA);
                    }
                }
            }
        }
        #pragma unroll
        for (int j = 0; j < 4; ++j) {
            accA[j] += accB[j];
            accA[j].x += __shfl_xor(accA[j].x, 16);
            accA[j].y += __shfl_xor(accA[j].y, 16);
            accA[j].x += __shfl_xor(accA[j].x, 32);
            accA[j].y += __shfl_xor(accA[j].y, 32);
        }
        if (q == 0) {
            uint4 o;
            o.x = pack2(accA[0].x, accA[0].y);
            o.y = pack2(accA[1].x, accA[1].y);
            o.z = pack2(accA[2].x, accA[2].y);
            o.w = pack2(accA[3].x, accA[3].y);
            *(uint4*)(sA + tl * 136 + sl * 8) = o;
        }
    }
    __syncthreads();

    // ---- phase 2: MFMA GEMM. wave w: rows (w&3)*16..+16, col-block (w>>2)*64..+64 ----
    const int wr    = (w & 3) * 16;
    const int cbase = (w >> 2) * 4;
    const int fr    = lane & 15;
    const int fq    = lane >> 4;

    f32x4 acc[4];
    #pragma unroll
    for (int cf = 0; cf < 4; ++cf) acc[cf] = (f32x4){0.f, 0.f, 0.f, 0.f};

    #pragma unroll
    for (int ks = 0; ks < 4; ++ks) {
        const bf16x8 a = *(const bf16x8*)(sA + (wr + fr) * 136 + ks * 32 + fq * 8);
        #pragma unroll
        for (int cf = 0; cf < 4; ++cf) {
            const bf16x8 b = *(const bf16x8*)(sB + ((cbase + cf) * 16 + fr) * 136 + ks * 32 + fq * 8);
            acc[cf] = __builtin_amdgcn_mfma_f32_16x16x32_bf16(a, b, acc[cf], 0, 0, 0);
        }
    }
    __syncthreads();   // all A-frag reads done before D overwrites sA

    // D -> sA as bf16 (C/D layout: col=lane&15, row=(lane>>4)*4+reg)
    #pragma unroll
    for (int cf = 0; cf < 4; ++cf) {
        #pragma unroll
        for (int j = 0; j < 4; ++j) {
            const int row = wr + fq * 4 + j;
            sA[row * 136 + (cbase + cf) * 16 + fr] = f2bf(acc[cf][j]);
        }
    }
    __syncthreads();

    // coalesced store into P
    #pragma unroll
    for (int i = 0; i < 2; ++i) {
        const int f = tid + i * 512;
        const int row = f >> 4, unit = f & 15;
        const int t = tile * TILE_T + row;
        if (t < TNODE)
            *(uint4*)(P + ((size_t)r * TNODE + t) * C + unit * 8) =
                *(const uint4*)(sA + row * 136 + unit * 8);
    }
}

// ---------------- kernel 3: per-node gather of bf16 arr rows (no atomics) ----------------
__global__ __launch_bounds__(256)
void out_gather_kernel(const u16* __restrict__ P, const int* __restrict__ offsets,
                       const int* __restrict__ count, const int* __restrict__ bsum,
                       const int* __restrict__ list, float* __restrict__ out) {
    const int lane = threadIdx.x & 63;
    const int n = blockIdx.x * 4 + (threadIdx.x >> 6);
    if (n >= NNODE) return;
    const int st = offsets[n] + bsum[n >> 8];
    const int en = st + count[n];
    float2 a0 = make_float2(0.f, 0.f), a1 = make_float2(0.f, 0.f);
    int i = st;
    for (; i + 2 <= en; i += 2) {
        const u32 v0 = ((const u32*)(P + (size_t)list[i] * C))[lane];
        const u32 v1 = ((const u32*)(P + (size_t)list[i + 1] * C))[lane];
        const float2 f0 = unpack_bf2(v0), f1 = unpack_bf2(v1);
        a0.x += f0.x; a0.y += f0.y;
        a1.x += f1.x; a1.y += f1.y;
    }
    if (i < en) {
        const float2 f0 = unpack_bf2(((const u32*)(P + (size_t)list[i] * C))[lane]);
        a0.x += f0.x; a0.y += f0.y;
    }
    a0.x += a1.x; a0.y += a1.y;
    ((float2*)(out + (size_t)n * C))[lane] = a0;
}

// ---------------- fallback: round-1 fused (no workspace) ----------------
__device__ __forceinline__ void add4(float4& acc, const float4& b) {
    acc.x += b.x; acc.y += b.y; acc.z += b.z; acc.w += b.w;
}
__global__ __launch_bounds__(256, 1)
void rgcn_fused_kernel(const float* __restrict__ x, const float* __restrict__ w,
                       const int* __restrict__ ptr, const int* __restrict__ idx,
                       const int* __restrict__ tgt, float* __restrict__ out) {
    __shared__ float sW[C * C];
    __shared__ float sAgg[TILE_T][C + 4];
    const int tid = threadIdx.x, tile = blockIdx.x, r = blockIdx.y;
    {
        const float4* src = (const float4*)(w + (size_t)r * C * C);
        float4* dst = (float4*)sW;
        #pragma unroll
        for (int i = 0; i < 16; ++i) dst[tid + i * 256] = src[tid + i * 256];
    }
    {
        const int tl = tid >> 2, g = tid & 3;
        const int t = tile * TILE_T + tl;
        float4 a[8];
        #pragma unroll
        for (int j = 0; j < 8; ++j) a[j] = make_float4(0.f, 0.f, 0.f, 0.f);
        if (t < TNODE) {
            const int* pr = ptr + (size_t)r * (TNODE + 1);
            const int* er = idx + (size_t)r * NEDGE;
            int e = (t == 0) ? 0 : pr[t];
            const int end = (t == TNODE - 1) ? NEDGE : pr[t + 1];
            for (; e < end; ++e) {
                const int s0 = er[e];
                const float4* r0 = (const float4*)(x + (size_t)s0 * C) + g * 8;
                #pragma unroll
                for (int j = 0; j < 8; ++j) add4(a[j], r0[j]);
            }
        }
        float* rowp = &sAgg[tl][g * 32];
        #pragma unroll
        for (int j = 0; j < 8; ++j) ((float4*)rowp)[j] = a[j];
    }
    __syncthreads();
    const int tg = tid >> 4, cg = tid & 15;
    float4 acc0[4], acc1[4];
    #pragma unroll
    for (int i = 0; i < 4; ++i) {
        acc0[i] = make_float4(0.f, 0.f, 0.f, 0.f);
        acc1[i] = make_float4(0.f, 0.f, 0.f, 0.f);
    }
    for (int k4 = 0; k4 < C / 4; ++k4) {
        float4 av[4];
        #pragma unroll
        for (int i = 0; i < 4; ++i) av[i] = *(const float4*)&sAgg[tg * 4 + i][k4 * 4];
        #pragma unroll
        for (int kk = 0; kk < 4; ++kk) {
            const int k = k4 * 4 + kk;
            const float4 w0 = *(const float4*)&sW[k * C + cg * 4];
            const float4 w1 = *(const float4*)&sW[k * C + 64 + cg * 4];
            #pragma unroll
            for (int i = 0; i < 4; ++i) {
                const float a = ((const float*)&av[i])[kk];
                fma4(acc0[i], a, w0.x, w0.y, w0.z, w0.w);
                fma4(acc1[i], a, w1.x, w1.y, w1.z, w1.w);
            }
        }
    }
    const int* tr = tgt + (size_t)r * TNODE;
    #pragma unroll
    for (int i = 0; i < 4; ++i) {
        const int t = tile * TILE_T + tg * 4 + i;
        if (t < TNODE) {
            const int node = tr[t];
            float* ob = out + (size_t)node * C + cg * 4;
            unsafeAtomicAdd(ob + 0, acc0[i].x);  unsafeAtomicAdd(ob + 1, acc0[i].y);
            unsafeAtomicAdd(ob + 2, acc0[i].z);  unsafeAtomicAdd(ob + 3, acc0[i].w);
            unsafeAtomicAdd(ob + 64, acc1[i].x); unsafeAtomicAdd(ob + 65, acc1[i].y);
            unsafeAtomicAdd(ob + 66, acc1[i].z); unsafeAtomicAdd(ob + 67, acc1[i].w);
        }
    }
}

extern "C" void kernel_launch(void* const* d_in, const int* in_sizes, int n_in,
                              void* d_out, int out_size, void* d_ws, size_t ws_size,
                              hipStream_t stream) {
    const float* x   = (const float*)d_in[0];
    const float* w   = (const float*)d_in[1];
    const int*   ptr = (const int*)d_in[2];
    const int*   idx = (const int*)d_in[3];
    const int*   tgt = (const int*)d_in[4];
    float* out = (float*)d_out;

    // workspace layout (135 MB, round-8 proven)
    const size_t WS_NEED = 135000000;
    char* base = (char*)d_ws;

    if (ws_size >= WS_NEED) {
        u16* P       = (u16*)(base + 0);          // 102.4 MB
        u16* xb      = (u16*)(base + 104000000);  //  25.6 MB
        u16* wtb     = (u16*)(base + 130000000);  //  0.26 MB
        int* count   = (int*)(base + 131000000);
        int* offsets = (int*)(base + 131500000);
        int* cursor  = (int*)(base + 132000000);
        int* bsum    = (int*)(base + 132500000);
        int* list    = (int*)(base + 133000000);  // 1.6 MB

        setup_kernel<<<NB_CVX + NB_CVW + NB_ZERO, 256, 0, stream>>>(x, xb, w, wtb, count);
        hist_kernel<<<(NENT + 255) / 256, 256, 0, stream>>>(tgt, count);
        scan1_kernel<<<NB_SCAN, 256, 0, stream>>>(count, bsum, offsets, cursor);
        scan2_kernel<<<1, 512, 0, stream>>>(bsum);
        fill_kernel<<<(NENT + 255) / 256, 256, 0, stream>>>(tgt, cursor, bsum, list);

        dim3 grid(NTILE, NREL);
        fused_gather_gemm_kernel<<<grid, 512, 0, stream>>>(xb, ptr, idx, wtb, P);

        out_gather_kernel<<<(NNODE + 3) / 4, 256, 0, stream>>>(P, offsets, count, bsum, list, out);
    } else {
        hipMemsetAsync(out, 0, (size_t)NNODE * C * sizeof(float), stream);
        dim3 grid(NTILE, NREL);
        rgcn_fused_kernel<<<grid, 256, 0, stream>>>(x, w, ptr, idx, tgt, out);
    }
}